// Round 6
// baseline (121.548 us; speedup 1.0000x reference)
//
#include <hip/hip_runtime.h>

#define MARGIN 0.3f
#define BIGF 1e30f
#define MAXC 64

constexpr int D = 256;

typedef __attribute__((ext_vector_type(8))) _Float16 f16x8;
typedef __attribute__((ext_vector_type(4))) _Float16 f16x4;
typedef __attribute__((ext_vector_type(4))) float f32x4;

__device__ __forceinline__ void gll16(const void* g, void* l) {
  __builtin_amdgcn_global_load_lds(
      (const __attribute__((address_space(1))) unsigned int*)g,
      (__attribute__((address_space(3))) unsigned int*)l, 16, 0, 0);
}

// ---- K0: fused f16 convert + row-norm + min-init + bucket fill ----
// (cnt[] zeroed by hipMemsetAsync before this kernel)
__global__ __launch_bounds__(256)
void k0_prep(const float* __restrict__ E, const int* __restrict__ labels,
             _Float16* __restrict__ H, float* __restrict__ sq,
             unsigned* __restrict__ minAll, unsigned* __restrict__ minSemi,
             int* __restrict__ cnt, int* __restrict__ members, int B) {
  int wave = threadIdx.x >> 6, lane = threadIdx.x & 63;
  int row = blockIdx.x * 4 + wave;
  if (row >= B) return;
  float4 v = *(const float4*)&E[(size_t)row * D + lane * 4];
  f16x4 h;
  h.x = (_Float16)v.x; h.y = (_Float16)v.y;
  h.z = (_Float16)v.z; h.w = (_Float16)v.w;
  *(f16x4*)&H[(size_t)row * D + lane * 4] = h;
  float s = v.x * v.x + v.y * v.y + v.z * v.z + v.w * v.w;
#pragma unroll
  for (int off = 32; off; off >>= 1) s += __shfl_xor(s, off);
  if (lane == 0) {
    sq[row] = s;
    minAll[row] = __float_as_uint(BIGF);
    minSemi[row] = __float_as_uint(BIGF);
    int lab = labels[row];
    int p = atomicAdd(&cnt[lab], 1);
    if (p < MAXC) members[lab * MAXC + p] = row;
  }
}

// ---- K1: hardest positive per row via bucket list (exact fp32 path) ----
__global__ __launch_bounds__(256)
void k1_dap(const float* __restrict__ E, const int* __restrict__ labels,
            const float* __restrict__ sq, const int* __restrict__ cnt,
            const int* __restrict__ members, float* __restrict__ d_ap,
            int* __restrict__ haspos, int B) {
  int wave = threadIdx.x >> 6, lane = threadIdx.x & 63;
  int i = blockIdx.x * 4 + wave;
  if (i >= B) return;
  float4 a = *(const float4*)&E[(size_t)i * D + lane * 4];
  int li = labels[i];
  int n = min(cnt[li], MAXC);
  float sqi = sq[i];
  float m = -BIGF;
  const int* mem = &members[li * MAXC];
  int p = 0;
  for (; p + 3 < n; p += 4) {
    int j0 = mem[p], j1 = mem[p + 1], j2 = mem[p + 2], j3 = mem[p + 3];
    float4 b0 = *(const float4*)&E[(size_t)j0 * D + lane * 4];
    float4 b1 = *(const float4*)&E[(size_t)j1 * D + lane * 4];
    float4 b2 = *(const float4*)&E[(size_t)j2 * D + lane * 4];
    float4 b3 = *(const float4*)&E[(size_t)j3 * D + lane * 4];
    float s0 = a.x * b0.x + a.y * b0.y + a.z * b0.z + a.w * b0.w;
    float s1 = a.x * b1.x + a.y * b1.y + a.z * b1.z + a.w * b1.w;
    float s2 = a.x * b2.x + a.y * b2.y + a.z * b2.z + a.w * b2.w;
    float s3 = a.x * b3.x + a.y * b3.y + a.z * b3.z + a.w * b3.w;
#pragma unroll
    for (int off = 32; off; off >>= 1) {
      s0 += __shfl_xor(s0, off);
      s1 += __shfl_xor(s1, off);
      s2 += __shfl_xor(s2, off);
      s3 += __shfl_xor(s3, off);
    }
    float d0 = fmaxf(sqi + sq[j0] - 2.f * s0, 0.f);
    float d1 = fmaxf(sqi + sq[j1] - 2.f * s1, 0.f);
    float d2 = fmaxf(sqi + sq[j2] - 2.f * s2, 0.f);
    float d3 = fmaxf(sqi + sq[j3] - 2.f * s3, 0.f);
    if (j0 != i) m = fmaxf(m, d0);
    if (j1 != i) m = fmaxf(m, d1);
    if (j2 != i) m = fmaxf(m, d2);
    if (j3 != i) m = fmaxf(m, d3);
  }
  for (; p < n; ++p) {
    int j = mem[p];
    if (j == i) continue;
    float4 b = *(const float4*)&E[(size_t)j * D + lane * 4];
    float s = a.x * b.x + a.y * b.y + a.z * b.z + a.w * b.w;
#pragma unroll
    for (int off = 32; off; off >>= 1) s += __shfl_xor(s, off);
    m = fmaxf(m, fmaxf(sqi + sq[j] - 2.f * s, 0.f));
  }
  if (lane == 0) {
    d_ap[i] = (n > 1) ? m : -BIGF;
    haspos[i] = (n > 1) ? 1 : 0;
  }
}

// ---- K2: f16 symmetric MFMA Gram, 2-phase double-buffered pipeline ----
// T3 minimum recipe: stage(kt+1) issued BEFORE compute(kt); the single
// __syncthreads per kt supplies the vmcnt(0)+barrier (loads drain hidden
// under ds_read+MFMA). T2 swizzle via pre-swizzled global source.
__global__ __launch_bounds__(256)
void k2_f16(const _Float16* __restrict__ H, const float* __restrict__ sq,
            const float* __restrict__ d_ap, const int* __restrict__ labels,
            unsigned* __restrict__ minAll, unsigned* __restrict__ minSemi, int T) {
  __shared__ _Float16 Ah[2][128][64], Bh[2][128][64];  // 64 KB dbuf
  __shared__ float sqI[128], sqJ[128], dapI[128], dapJ[128];
  __shared__ int labI[128], labJ[128];
  __shared__ unsigned smAI[128], smSI[128], smAJ[128], smSJ[128];

  const int tid = threadIdx.x;
  const int lane = tid & 63;
  const int wave = tid >> 6;
  const int wr = wave >> 1, wc = wave & 1;
  const int lo4 = lane & 15, hi4 = lane >> 4;
  const int wbase = tid & 192;
  const int swc = lo4 & 7;

  const int nwg = gridDim.x;
  const int bid = blockIdx.x;
  const int swz = ((nwg & 7) == 0) ? (bid & 7) * (nwg >> 3) + (bid >> 3) : bid;
  int ti = (int)((sqrtf(8.f * (float)swz + 1.f) - 1.f) * 0.5f);
  while ((ti + 1) * (ti + 2) / 2 <= swz) ++ti;
  while (ti * (ti + 1) / 2 > swz) --ti;
  const int tj = swz - ti * (ti + 1) / 2;
  const int iBase = ti * 128, jBase = tj * 128;

  auto stage = [&](int buf, int kt) {
    const int k0 = kt * 64;
#pragma unroll
    for (int p = 0; p < 4; ++p) {
      int f = p * 256 + tid;
      int row = f >> 3;
      int ch = (f & 7) ^ (row & 7);  // inverse swizzle on per-lane source
      size_t sI = (size_t)(iBase + row) * D + k0 + ch * 8;
      size_t sJ = (size_t)(jBase + row) * D + k0 + ch * 8;
      size_t lOff = (size_t)(p * 256 + wbase) * 8;  // linear LDS dest
      gll16(H + sI, &Ah[buf][0][0] + lOff);
      gll16(H + sJ, &Bh[buf][0][0] + lOff);
    }
  };

  if (tid < 128) {
    int gi = iBase + tid, gj = jBase + tid;
    sqI[tid] = sq[gi]; labI[tid] = labels[gi]; dapI[tid] = d_ap[gi];
    sqJ[tid] = sq[gj]; labJ[tid] = labels[gj]; dapJ[tid] = d_ap[gj];
    smAI[tid] = smSI[tid] = smAJ[tid] = smSJ[tid] = __float_as_uint(BIGF);
  }

  f32x4 acc[4][4];
#pragma unroll
  for (int m = 0; m < 4; ++m)
#pragma unroll
    for (int n = 0; n < 4; ++n) acc[m][n] = (f32x4){0.f, 0.f, 0.f, 0.f};

  stage(0, 0);
  __syncthreads();  // drain stage0; smem init visible

  int cur = 0;
  for (int kt = 0; kt < 4; ++kt) {
    if (kt < 3) stage(cur ^ 1, kt + 1);  // issue next-chunk loads FIRST
#pragma unroll
    for (int ks = 0; ks < 2; ++ks) {
      f16x8 aF[4], bF[4];
#pragma unroll
      for (int m = 0; m < 4; ++m) {
        const int col = (((ks << 2) | hi4) ^ swc) << 3;
        aF[m] = *(const f16x8*)&Ah[cur][wr * 64 + m * 16 + lo4][col];
      }
#pragma unroll
      for (int n = 0; n < 4; ++n) {
        const int col = (((ks << 2) | hi4) ^ swc) << 3;
        bF[n] = *(const f16x8*)&Bh[cur][wc * 64 + n * 16 + lo4][col];
      }
#pragma unroll
      for (int m = 0; m < 4; ++m)
#pragma unroll
        for (int n = 0; n < 4; ++n)
          acc[m][n] = __builtin_amdgcn_mfma_f32_16x16x32_f16(aF[m], bF[n], acc[m][n], 0, 0, 0);
    }
    __syncthreads();  // vmcnt(0)+lgkmcnt(0)+barrier: next buf ready, cur reusable
    cur ^= 1;
  }

  // ---- row-side epilogue: anchors = i-rows, candidates = j-cols ----
#pragma unroll
  for (int m = 0; m < 4; ++m) {
#pragma unroll
    for (int reg = 0; reg < 4; ++reg) {
      const int li = wr * 64 + m * 16 + hi4 * 4 + reg;
      const float si = sqI[li], da = dapI[li];
      const int lbi = labI[li];
      float rA = BIGF, rS = BIGF;
#pragma unroll
      for (int n = 0; n < 4; ++n) {
        const int lj = wc * 64 + n * 16 + lo4;
        float dd = fmaxf(si + sqJ[lj] - 2.f * acc[m][n][reg], 0.f);
        if (labJ[lj] != lbi) {
          rA = fminf(rA, dd);
          if (dd > da && dd < da + MARGIN) rS = fminf(rS, dd);
        }
      }
#pragma unroll
      for (int off = 1; off < 16; off <<= 1) {
        rA = fminf(rA, __shfl_xor(rA, off));
        rS = fminf(rS, __shfl_xor(rS, off));
      }
      if (lo4 == 0) {
        atomicMin(&smAI[li], __float_as_uint(rA));
        atomicMin(&smSI[li], __float_as_uint(rS));
      }
    }
  }
  // ---- col-side epilogue: anchors = j-rows, candidates = i-cols ----
#pragma unroll
  for (int n = 0; n < 4; ++n) {
    const int lj = wc * 64 + n * 16 + lo4;
    const float sj = sqJ[lj], dj = dapJ[lj];
    const int lbj = labJ[lj];
    float cA = BIGF, cS = BIGF;
#pragma unroll
    for (int m = 0; m < 4; ++m)
#pragma unroll
      for (int reg = 0; reg < 4; ++reg) {
        const int li = wr * 64 + m * 16 + hi4 * 4 + reg;
        float dd = fmaxf(sqI[li] + sj - 2.f * acc[m][n][reg], 0.f);
        if (labI[li] != lbj) {
          cA = fminf(cA, dd);
          if (dd > dj && dd < dj + MARGIN) cS = fminf(cS, dd);
        }
      }
    cA = fminf(cA, __shfl_xor(cA, 16));
    cS = fminf(cS, __shfl_xor(cS, 16));
    cA = fminf(cA, __shfl_xor(cA, 32));
    cS = fminf(cS, __shfl_xor(cS, 32));
    if (hi4 == 0) {
      atomicMin(&smAJ[lj], __float_as_uint(cA));
      atomicMin(&smSJ[lj], __float_as_uint(cS));
    }
  }
  __syncthreads();
  if (tid < 128) {
    atomicMin(&minAll[iBase + tid], smAI[tid]);
    atomicMin(&minSemi[iBase + tid], smSI[tid]);
    atomicMin(&minAll[jBase + tid], smAJ[tid]);
    atomicMin(&minSemi[jBase + tid], smSJ[tid]);
  }
}

// ---- K3: deterministic final reduction ----
__global__ __launch_bounds__(1024)
void k3_final(const float* __restrict__ d_ap, const int* __restrict__ haspos,
              const unsigned* __restrict__ minAll, const unsigned* __restrict__ minSemi,
              float* __restrict__ out, int B) {
  __shared__ float ssum[1024];
  __shared__ int scnt[1024];
  int t = threadIdx.x;
  float lsum = 0.f;
  int lcnt = 0;
  for (int i = t; i < B; i += 1024) {
    float mA = __uint_as_float(minAll[i]);
    float mS = __uint_as_float(minSemi[i]);
    float dan = (mS < 1e29f) ? mS : mA;
    float loss = fmaxf(d_ap[i] - dan + MARGIN, 0.f);
    if (haspos[i]) { lsum += loss; lcnt += 1; }
  }
  ssum[t] = lsum;
  scnt[t] = lcnt;
  __syncthreads();
  for (int off = 512; off; off >>= 1) {
    if (t < off) { ssum[t] += ssum[t + off]; scnt[t] += scnt[t + off]; }
    __syncthreads();
  }
  if (t == 0) out[0] = ssum[0] / (float)max(scnt[0], 1);
}

extern "C" void kernel_launch(void* const* d_in, const int* in_sizes, int n_in,
                              void* d_out, int out_size, void* d_ws, size_t ws_size,
                              hipStream_t stream) {
  const float* E = (const float*)d_in[0];
  const int* labels = (const int*)d_in[1];
  int B = in_sizes[1];

  float* ws = (float*)d_ws;
  float* sq = ws;                                   // [B]
  float* dap = ws + B;                              // [B]
  int* haspos = (int*)(ws + 2 * B);                 // [B]
  unsigned* minAll = (unsigned*)(ws + 3 * B);       // [B]
  unsigned* minSemi = (unsigned*)(ws + 4 * B);      // [B]
  int* cnt = (int*)(ws + 5 * B);                    // [512]
  int* members = cnt + 512;                         // [512*MAXC]
  _Float16* H = (_Float16*)(members + 512 * MAXC);  // [B*D] f16
  float* out = (float*)d_out;

  hipMemsetAsync(cnt, 0, 512 * sizeof(int), stream);
  k0_prep<<<(B + 3) / 4, 256, 0, stream>>>(E, labels, H, sq, minAll, minSemi, cnt, members, B);
  k1_dap<<<(B + 3) / 4, 256, 0, stream>>>(E, labels, sq, cnt, members, dap, haspos, B);
  int T = B / 128;
  int nwg = T * (T + 1) / 2;
  k2_f16<<<nwg, 256, 0, stream>>>(H, sq, dap, labels, minAll, minSemi, T);
  k3_final<<<1, 1024, 0, stream>>>(dap, haspos, minAll, minSemi, out, B);
}

// Round 7
// 108.110 us; speedup vs baseline: 1.1243x; 1.1243x over previous
//
#include <hip/hip_runtime.h>

#define MARGIN 0.3f
#define BIGF 1e30f
#define MAXC 64

constexpr int D = 256;

typedef __attribute__((ext_vector_type(8))) _Float16 f16x8;
typedef __attribute__((ext_vector_type(4))) _Float16 f16x4;
typedef __attribute__((ext_vector_type(4))) float f32x4;

__device__ __forceinline__ void gll16(const void* g, void* l) {
  __builtin_amdgcn_global_load_lds(
      (const __attribute__((address_space(1))) unsigned int*)g,
      (__attribute__((address_space(3))) unsigned int*)l, 16, 0, 0);
}

#define SCB() __builtin_amdgcn_sched_barrier(0)
#define BAR() __builtin_amdgcn_s_barrier()

// ---- K0: fused f16 convert + row-norm + min-init + bucket fill ----
__global__ __launch_bounds__(256)
void k0_prep(const float* __restrict__ E, const int* __restrict__ labels,
             _Float16* __restrict__ H, float* __restrict__ sq,
             unsigned* __restrict__ minAll, unsigned* __restrict__ minAb,
             int* __restrict__ cnt, int* __restrict__ members, int B) {
  int wave = threadIdx.x >> 6, lane = threadIdx.x & 63;
  int row = blockIdx.x * 4 + wave;
  if (row >= B) return;
  float4 v = *(const float4*)&E[(size_t)row * D + lane * 4];
  f16x4 h;
  h.x = (_Float16)v.x; h.y = (_Float16)v.y;
  h.z = (_Float16)v.z; h.w = (_Float16)v.w;
  *(f16x4*)&H[(size_t)row * D + lane * 4] = h;
  float s = v.x * v.x + v.y * v.y + v.z * v.z + v.w * v.w;
#pragma unroll
  for (int off = 32; off; off >>= 1) s += __shfl_xor(s, off);
  if (lane == 0) {
    sq[row] = s;
    minAll[row] = __float_as_uint(BIGF);
    minAb[row] = __float_as_uint(BIGF);
    int lab = labels[row];
    int p = atomicAdd(&cnt[lab], 1);
    if (p < MAXC) members[lab * MAXC + p] = row;
  }
}

// ---- K1: hardest positive per row via bucket list (exact fp32 path) ----
__global__ __launch_bounds__(256)
void k1_dap(const float* __restrict__ E, const int* __restrict__ labels,
            const float* __restrict__ sq, const int* __restrict__ cnt,
            const int* __restrict__ members, float* __restrict__ d_ap,
            int* __restrict__ haspos, int B) {
  int wave = threadIdx.x >> 6, lane = threadIdx.x & 63;
  int i = blockIdx.x * 4 + wave;
  if (i >= B) return;
  float4 a = *(const float4*)&E[(size_t)i * D + lane * 4];
  int li = labels[i];
  int n = min(cnt[li], MAXC);
  float sqi = sq[i];
  float m = -BIGF;
  const int* mem = &members[li * MAXC];
  int p = 0;
  for (; p + 3 < n; p += 4) {
    int j0 = mem[p], j1 = mem[p + 1], j2 = mem[p + 2], j3 = mem[p + 3];
    float4 b0 = *(const float4*)&E[(size_t)j0 * D + lane * 4];
    float4 b1 = *(const float4*)&E[(size_t)j1 * D + lane * 4];
    float4 b2 = *(const float4*)&E[(size_t)j2 * D + lane * 4];
    float4 b3 = *(const float4*)&E[(size_t)j3 * D + lane * 4];
    float s0 = a.x * b0.x + a.y * b0.y + a.z * b0.z + a.w * b0.w;
    float s1 = a.x * b1.x + a.y * b1.y + a.z * b1.z + a.w * b1.w;
    float s2 = a.x * b2.x + a.y * b2.y + a.z * b2.z + a.w * b2.w;
    float s3 = a.x * b3.x + a.y * b3.y + a.z * b3.z + a.w * b3.w;
#pragma unroll
    for (int off = 32; off; off >>= 1) {
      s0 += __shfl_xor(s0, off);
      s1 += __shfl_xor(s1, off);
      s2 += __shfl_xor(s2, off);
      s3 += __shfl_xor(s3, off);
    }
    float d0 = fmaxf(sqi + sq[j0] - 2.f * s0, 0.f);
    float d1 = fmaxf(sqi + sq[j1] - 2.f * s1, 0.f);
    float d2 = fmaxf(sqi + sq[j2] - 2.f * s2, 0.f);
    float d3 = fmaxf(sqi + sq[j3] - 2.f * s3, 0.f);
    if (j0 != i) m = fmaxf(m, d0);
    if (j1 != i) m = fmaxf(m, d1);
    if (j2 != i) m = fmaxf(m, d2);
    if (j3 != i) m = fmaxf(m, d3);
  }
  for (; p < n; ++p) {
    int j = mem[p];
    if (j == i) continue;
    float4 b = *(const float4*)&E[(size_t)j * D + lane * 4];
    float s = a.x * b.x + a.y * b.y + a.z * b.z + a.w * b.w;
#pragma unroll
    for (int off = 32; off; off >>= 1) s += __shfl_xor(s, off);
    m = fmaxf(m, fmaxf(sqi + sq[j] - 2.f * s, 0.f));
  }
  if (lane == 0) {
    d_ap[i] = (n > 1) ? m : -BIGF;
    haspos[i] = (n > 1) ? 1 : 0;
  }
}

// ---- K2: 256x256 f16 symmetric Gram, counted-vmcnt double-buffer -------
// 8 waves (2M x 4N), per-wave 128x64, acc[8][4]. Raw s_barrier + vmcnt(8)
// keeps next tile's 8 loads in flight across the barrier (T3+T4). T2
// swizzle via pre-swizzled global source (conflicts=0, verified R4).
__global__ __launch_bounds__(512)
void k2_f16(const _Float16* __restrict__ H, const float* __restrict__ sq,
            const float* __restrict__ d_ap, const int* __restrict__ labels,
            unsigned* __restrict__ minAll, unsigned* __restrict__ minAb, int T) {
  __shared__ _Float16 Ah[2][256][64], Bh[2][256][64];  // 128 KB
  __shared__ float sqI[256], sqJ[256], dapI[256], dapJ[256];
  __shared__ int labI[256], labJ[256];
  __shared__ unsigned smAI[256], smBI[256], smAJ[256], smBJ[256];

  const int tid = threadIdx.x;
  const int lane = tid & 63;
  const int wave = tid >> 6;
  const int wr = wave >> 2, wc = wave & 3;
  const int lo4 = lane & 15, hi4 = lane >> 4;
  const int swc = lo4 & 7;

  const int nwg = gridDim.x;
  const int bid = blockIdx.x;
  const int swz = ((nwg & 7) == 0) ? (bid & 7) * (nwg >> 3) + (bid >> 3) : bid;
  int ti = (int)((sqrtf(8.f * (float)swz + 1.f) - 1.f) * 0.5f);
  while ((ti + 1) * (ti + 2) / 2 <= swz) ++ti;
  while (ti * (ti + 1) / 2 > swz) --ti;
  const int tj = swz - ti * (ti + 1) / 2;
  const int iBase = ti * 256, jBase = tj * 256;
  const bool offdiag = (ti != tj);

  // per-thread staging source pointers (swizzled chunk, constant across kt)
  const int r0 = tid >> 3;
  const int ch = (tid & 7) ^ (r0 & 7);
  const _Float16* srcA[4];
  const _Float16* srcB[4];
#pragma unroll
  for (int p = 0; p < 4; ++p) {
    srcA[p] = H + (size_t)(iBase + p * 64 + r0) * D + ch * 8;
    srcB[p] = H + (size_t)(jBase + p * 64 + r0) * D + ch * 8;
  }

  auto STAGE = [&](int buf, int kt) {
    _Float16* la = &Ah[buf][0][0] + tid * 8;
    _Float16* lb = &Bh[buf][0][0] + tid * 8;
#pragma unroll
    for (int p = 0; p < 4; ++p) {
      gll16(srcA[p] + kt * 64, la + p * 4096);
      gll16(srcB[p] + kt * 64, lb + p * 4096);
    }
  };

  f32x4 acc[8][4];
#pragma unroll
  for (int m = 0; m < 8; ++m)
#pragma unroll
    for (int n = 0; n < 4; ++n) acc[m][n] = (f32x4){0.f, 0.f, 0.f, 0.f};

  auto COMPUTE = [&](int buf) {
#pragma unroll
    for (int ks = 0; ks < 2; ++ks) {
      f16x8 aF[8], bF[4];
#pragma unroll
      for (int m = 0; m < 8; ++m) {
        const int pc = (((ks << 2) | hi4) ^ swc);
        aF[m] = *(const f16x8*)&Ah[buf][wr * 128 + m * 16 + lo4][pc * 8];
      }
#pragma unroll
      for (int n = 0; n < 4; ++n) {
        const int pc = (((ks << 2) | hi4) ^ swc);
        bF[n] = *(const f16x8*)&Bh[buf][wc * 64 + n * 16 + lo4][pc * 8];
      }
#pragma unroll
      for (int m = 0; m < 8; ++m)
#pragma unroll
        for (int n = 0; n < 4; ++n)
          acc[m][n] = __builtin_amdgcn_mfma_f32_16x16x32_f16(aF[m], bF[n], acc[m][n], 0, 0, 0);
    }
  };

  STAGE(0, 0);
  if (tid < 256) {
    int gi = iBase + tid, gj = jBase + tid;
    sqI[tid] = sq[gi]; labI[tid] = labels[gi]; dapI[tid] = d_ap[gi];
    sqJ[tid] = sq[gj]; labJ[tid] = labels[gj]; dapJ[tid] = d_ap[gj];
    smAI[tid] = smBI[tid] = smAJ[tid] = smBJ[tid] = __float_as_uint(BIGF);
  }

  STAGE(1, 1);
  asm volatile("s_waitcnt vmcnt(8) lgkmcnt(0)" ::: "memory");
  SCB(); BAR(); SCB();
  COMPUTE(0);
  BAR(); SCB();

  STAGE(0, 2);
  asm volatile("s_waitcnt vmcnt(8)" ::: "memory");
  SCB(); BAR(); SCB();
  COMPUTE(1);
  BAR(); SCB();

  STAGE(1, 3);
  asm volatile("s_waitcnt vmcnt(8)" ::: "memory");
  SCB(); BAR(); SCB();
  COMPUTE(0);
  BAR(); SCB();

  asm volatile("s_waitcnt vmcnt(0)" ::: "memory");
  SCB(); BAR(); SCB();
  COMPUTE(1);

  // ---- fused epilogue: one sweep feeds both row-side and col-side minima
  float sjv[4], djv[4];
  int ljv[4];
#pragma unroll
  for (int n = 0; n < 4; ++n) {
    int lj = wc * 64 + n * 16 + lo4;
    sjv[n] = sqJ[lj];
    djv[n] = dapJ[lj];
    ljv[n] = labJ[lj];
  }
  float cA[4], cB[4];
#pragma unroll
  for (int n = 0; n < 4; ++n) { cA[n] = BIGF; cB[n] = BIGF; }

#pragma unroll
  for (int m = 0; m < 8; ++m) {
#pragma unroll
    for (int reg = 0; reg < 4; ++reg) {
      const int li = wr * 128 + m * 16 + hi4 * 4 + reg;
      const float si = sqI[li], da = dapI[li];
      const int lbi = labI[li];
      float rA = BIGF, rB = BIGF;
#pragma unroll
      for (int n = 0; n < 4; ++n) {
        float dd = fmaxf(fmaf(-2.f, acc[m][n][reg], si + sjv[n]), 0.f);
        float ddm = (ljv[n] != lbi) ? dd : BIGF;
        rA = fminf(rA, ddm);
        rB = fminf(rB, (ddm > da) ? ddm : BIGF);
        if (offdiag) {
          cA[n] = fminf(cA[n], ddm);
          cB[n] = fminf(cB[n], (ddm > djv[n]) ? ddm : BIGF);
        }
      }
#pragma unroll
      for (int off = 1; off < 16; off <<= 1) {
        rA = fminf(rA, __shfl_xor(rA, off));
        rB = fminf(rB, __shfl_xor(rB, off));
      }
      if (lo4 == 0) {
        atomicMin(&smAI[li], __float_as_uint(rA));
        atomicMin(&smBI[li], __float_as_uint(rB));
      }
    }
  }
  if (offdiag) {
#pragma unroll
    for (int n = 0; n < 4; ++n) {
      const int lj = wc * 64 + n * 16 + lo4;
      float a = cA[n], b = cB[n];
      a = fminf(a, __shfl_xor(a, 16)); b = fminf(b, __shfl_xor(b, 16));
      a = fminf(a, __shfl_xor(a, 32)); b = fminf(b, __shfl_xor(b, 32));
      if (hi4 == 0) {
        atomicMin(&smAJ[lj], __float_as_uint(a));
        atomicMin(&smBJ[lj], __float_as_uint(b));
      }
    }
  }
  __syncthreads();
  if (tid < 256) {
    atomicMin(&minAll[iBase + tid], smAI[tid]);
    atomicMin(&minAb[iBase + tid], smBI[tid]);
    if (offdiag) {
      atomicMin(&minAll[jBase + tid], smAJ[tid]);
      atomicMin(&minAb[jBase + tid], smBJ[tid]);
    }
  }
}

// ---- K3: deterministic final reduction ----
// d_an = minAbove if minAbove < d_ap + margin (a semi-hard exists), else minAll.
__global__ __launch_bounds__(1024)
void k3_final(const float* __restrict__ d_ap, const int* __restrict__ haspos,
              const unsigned* __restrict__ minAll, const unsigned* __restrict__ minAb,
              float* __restrict__ out, int B) {
  __shared__ float ssum[1024];
  __shared__ int scnt[1024];
  int t = threadIdx.x;
  float lsum = 0.f;
  int lcnt = 0;
  for (int i = t; i < B; i += 1024) {
    float mA = __uint_as_float(minAll[i]);
    float mB = __uint_as_float(minAb[i]);
    float dap = d_ap[i];
    float dan = (mB < dap + MARGIN) ? mB : mA;
    float loss = fmaxf(dap - dan + MARGIN, 0.f);
    if (haspos[i]) { lsum += loss; lcnt += 1; }
  }
  ssum[t] = lsum;
  scnt[t] = lcnt;
  __syncthreads();
  for (int off = 512; off; off >>= 1) {
    if (t < off) { ssum[t] += ssum[t + off]; scnt[t] += scnt[t + off]; }
    __syncthreads();
  }
  if (t == 0) out[0] = ssum[0] / (float)max(scnt[0], 1);
}

extern "C" void kernel_launch(void* const* d_in, const int* in_sizes, int n_in,
                              void* d_out, int out_size, void* d_ws, size_t ws_size,
                              hipStream_t stream) {
  const float* E = (const float*)d_in[0];
  const int* labels = (const int*)d_in[1];
  int B = in_sizes[1];

  float* ws = (float*)d_ws;
  float* sq = ws;                                   // [B]
  float* dap = ws + B;                              // [B]
  int* haspos = (int*)(ws + 2 * B);                 // [B]
  unsigned* minAll = (unsigned*)(ws + 3 * B);       // [B]
  unsigned* minAb = (unsigned*)(ws + 4 * B);        // [B]
  int* cnt = (int*)(ws + 5 * B);                    // [512]
  int* members = cnt + 512;                         // [512*MAXC]
  _Float16* H = (_Float16*)(members + 512 * MAXC);  // [B*D] f16
  float* out = (float*)d_out;

  hipMemsetAsync(cnt, 0, 512 * sizeof(int), stream);
  k0_prep<<<(B + 3) / 4, 256, 0, stream>>>(E, labels, H, sq, minAll, minAb, cnt, members, B);
  k1_dap<<<(B + 3) / 4, 256, 0, stream>>>(E, labels, sq, cnt, members, dap, haspos, B);
  int T = B / 256;
  int nwg = T * (T + 1) / 2;
  k2_f16<<<nwg, 512, 0, stream>>>(H, sq, dap, labels, minAll, minAb, T);
  k3_final<<<1, 1024, 0, stream>>>(dap, haspos, minAll, minAb, out, B);
}